// Round 4
// baseline (484.256 us; speedup 1.0000x reference)
//
#include <hip/hip_runtime.h>
#include <stdint.h>
#include <stddef.h>

#define N_NODES 8192
#define N_FEAT  512
#define EMB     128
#define N_HEADS 4
#define TILE    128
#define TG      (N_NODES / TILE)        // 64
#define NPAIR   (TG * (TG + 1) / 2)     // 2080

typedef __attribute__((ext_vector_type(8)))  short bf16x8;
typedef __attribute__((ext_vector_type(16))) float f32x16;

__device__ __forceinline__ unsigned short f2bf(float f) {
  union { float f; unsigned int u; } x; x.f = f;
  unsigned int r = (x.u + 0x7FFFu + ((x.u >> 16) & 1u)) >> 16;
  return (unsigned short)r;
}
__device__ __forceinline__ float bf2f(unsigned short u) {
  union { unsigned int u; float f; } x; x.u = ((unsigned int)u) << 16;
  return x.f;
}

// Tbuf (bf16 [128][128]) XOR-swizzled index, low-conflict both orientations
__device__ __forceinline__ int tidx(int r, int c) {
  int m = (r & 31) ^ ((r & 4) << 2);
  return r * 128 + (c ^ m);
}

// ---------- kernel 1: X_emb = X@W, row-normalize, cast bf16, row-major write ----------
__global__ void __launch_bounds__(512) xw_kernel(const float* __restrict__ X,
                                                 const float* __restrict__ W,
                                                 unsigned short* __restrict__ Xen) {
  __shared__ float xs[32][N_FEAT];    // 64KB
  const int t = threadIdx.x;
  const int row0 = blockIdx.x * 32;
#pragma unroll
  for (int i = 0; i < 8; ++i) {
    int e4 = i * 512 + t;             // float4 index, 4096 total
    int row = e4 >> 7;                // 128 float4 per row
    int col = (e4 & 127) * 4;
    *(float4*)&xs[row][col] = *(const float4*)&X[(size_t)(row0 + row) * N_FEAT + col];
  }
  __syncthreads();
  const int c0 = (t & 31) * 4;
  const int r0 = (t >> 5) * 2;
  float a00=0.f,a01=0.f,a02=0.f,a03=0.f,a10=0.f,a11=0.f,a12=0.f,a13=0.f;
  for (int k = 0; k < N_FEAT; k += 2) {
    float4 w0 = *(const float4*)&W[(size_t)k * EMB + c0];
    float4 w1 = *(const float4*)&W[(size_t)(k + 1) * EMB + c0];
    float x00 = xs[r0][k],     x01 = xs[r0][k + 1];
    float x10 = xs[r0 + 1][k], x11 = xs[r0 + 1][k + 1];
    a00 += x00*w0.x; a01 += x00*w0.y; a02 += x00*w0.z; a03 += x00*w0.w;
    a10 += x10*w0.x; a11 += x10*w0.y; a12 += x10*w0.z; a13 += x10*w0.w;
    a00 += x01*w1.x; a01 += x01*w1.y; a02 += x01*w1.z; a03 += x01*w1.w;
    a10 += x11*w1.x; a11 += x11*w1.y; a12 += x11*w1.z; a13 += x11*w1.w;
  }
  float s0 = a00*a00 + a01*a01 + a02*a02 + a03*a03;
  float s1 = a10*a10 + a11*a11 + a12*a12 + a13*a13;
#pragma unroll
  for (int off = 16; off >= 1; off >>= 1) {
    s0 += __shfl_xor(s0, off);
    s1 += __shfl_xor(s1, off);
  }
  float inv0 = 1.0f / (sqrtf(s0) + 1e-6f);
  float inv1 = 1.0f / (sqrtf(s1) + 1e-6f);
  union { unsigned short u[4]; uint2 v; } o0, o1;
  o0.u[0]=f2bf(a00*inv0); o0.u[1]=f2bf(a01*inv0); o0.u[2]=f2bf(a02*inv0); o0.u[3]=f2bf(a03*inv0);
  o1.u[0]=f2bf(a10*inv1); o1.u[1]=f2bf(a11*inv1); o1.u[2]=f2bf(a12*inv1); o1.u[3]=f2bf(a13*inv1);
  int n0 = row0 + r0;
  *(uint2*)&Xen[(size_t)n0 * EMB + c0] = o0.v;
  *(uint2*)&Xen[(size_t)(n0 + 1) * EMB + c0] = o1.v;
}

// ---------- kernel 2: Z row-normalize + bf16, row-major write ----------
__global__ void __launch_bounds__(256) znorm_kernel(const float* __restrict__ in,
                                                    unsigned short* __restrict__ out) {
  const int row = blockIdx.x * 4 + (threadIdx.x >> 6);
  const int lane = threadIdx.x & 63;
  float2 v = *(const float2*)&in[(size_t)row * EMB + lane * 2];
  float ss = v.x * v.x + v.y * v.y;
#pragma unroll
  for (int off = 32; off >= 1; off >>= 1) ss += __shfl_xor(ss, off);
  const float s = 1.0f / (sqrtf(ss) + 1e-6f);
  union { unsigned short u[2]; unsigned int w; } o;
  o.u[0] = f2bf(v.x * s);
  o.u[1] = f2bf(v.y * s);
  *(unsigned int*)&out[(size_t)row * EMB + lane * 2] = o.w;
}

// ---------- kernel 3: fused affinity, no-LDS K-loop ----------
__global__ void __launch_bounds__(512, 2)
affinity_kernel(const unsigned short* __restrict__ Xen,
                const unsigned short* __restrict__ Zn,
                const float* __restrict__ betap,
                float* __restrict__ out) {
  __shared__ unsigned short Tb[TILE * TILE];  // 32 KB bf16 transpose buffer

  // XCD-bijective swizzle (2080 % 8 == 0)
  int bid = blockIdx.x;
  int p = (bid & 7) * (NPAIR / 8) + (bid >> 3);
  // triangular decode p -> (bi <= bj)
  int i = (int)(((float)(2 * TG + 1) -
                 sqrtf((float)((2 * TG + 1) * (2 * TG + 1) - 8 * p))) * 0.5f);
  if (i < 0) i = 0;
  if (i > TG - 1) i = TG - 1;
  while (i > 0 && i * TG - i * (i - 1) / 2 > p) --i;
  while ((i + 1) * TG - (i + 1) * i / 2 <= p) ++i;
  const int bi = i;
  const int bj = i + (p - (i * TG - i * (i - 1) / 2));
  const bool diag = (bi == bj);

  const int t = threadIdx.x;
  const int lane = t & 63;
  const int wid = t >> 6;
  const int R0 = (wid >> 1) * 32;    // 4 row-groups of 32
  const int C0 = (wid & 1) * 64;     // 2 col-groups of 64
  const int fr = lane & 31;
  const int fh = lane >> 5;
  const int koff = fh * 8;

  const size_t HSTRIDE = (size_t)N_NODES * EMB;
  const size_t zi_base = (size_t)bi * TILE * EMB;
  const size_t zj_base = (size_t)bj * TILE * EMB;
  const int arow  = (R0 + fr) * EMB + koff;
  const int xrow0 = (C0 + fr) * EMB + koff;
  const int xrow1 = (C0 + 32 + fr) * EMB + koff;

  // X B-fragments -> registers (phase I: bj tile)
  bf16x8 XB0[8], XB1[8];
  {
    const unsigned short* xj = Xen + zj_base;
#pragma unroll
    for (int kk = 0; kk < 8; ++kk) {
      XB0[kk] = *(const bf16x8*)&xj[xrow0 + kk * 16];
      XB1[kk] = *(const bf16x8*)&xj[xrow1 + kk * 16];
    }
  }

  // A-fragment register double buffer; preload stage 0 (h=0, bi)
  bf16x8 A0[8], A1[8];
#pragma unroll
  for (int kk = 0; kk < 8; ++kk)
    A0[kk] = *(const bf16x8*)&Zn[zi_base + arow + kk * 16];

  f32x16 maxI0, maxI1;
#pragma unroll
  for (int q = 0; q < 16; ++q) { maxI0[q] = -3.0e38f; maxI1[q] = -3.0e38f; }

  // ---- phase I: 4 heads, A = Z[h][bi-rows], B = Xj ----
#pragma unroll
  for (int s = 0; s < 4; ++s) {
    bf16x8 (&cur)[8] = (s & 1) ? A1 : A0;
    bf16x8 (&nxt)[8] = (s & 1) ? A0 : A1;
    if (s < 3) {
      const unsigned short* nsrc = Zn + (size_t)(s + 1) * HSTRIDE + zi_base;
#pragma unroll
      for (int kk = 0; kk < 8; ++kk) nxt[kk] = *(const bf16x8*)&nsrc[arow + kk * 16];
    } else if (!diag) {
      const unsigned short* nsrc = Zn + zj_base;   // h=0, bj (phase J stage 0)
#pragma unroll
      for (int kk = 0; kk < 8; ++kk) nxt[kk] = *(const bf16x8*)&nsrc[arow + kk * 16];
    }
    f32x16 acc0 = {}, acc1 = {};
#pragma unroll
    for (int kk = 0; kk < 8; ++kk) {
      acc0 = __builtin_amdgcn_mfma_f32_32x32x16_bf16(cur[kk], XB0[kk], acc0, 0, 0, 0);
      acc1 = __builtin_amdgcn_mfma_f32_32x32x16_bf16(cur[kk], XB1[kk], acc1, 0, 0, 0);
    }
#pragma unroll
    for (int q = 0; q < 16; ++q) {
      maxI0[q] = fmaxf(maxI0[q], acc0[q]);
      maxI1[q] = fmaxf(maxI1[q], acc1[q]);
    }
  }

  f32x16 maxJ0, maxJ1;
#pragma unroll
  for (int q = 0; q < 16; ++q) { maxJ0[q] = -3.0e38f; maxJ1[q] = -3.0e38f; }

  // ---- phase J: 4 heads, A = Z[h][bj-rows], B = Xi ----
  if (!diag) {
    const unsigned short* xi = Xen + zi_base;
#pragma unroll
    for (int kk = 0; kk < 8; ++kk) {
      XB0[kk] = *(const bf16x8*)&xi[xrow0 + kk * 16];
      XB1[kk] = *(const bf16x8*)&xi[xrow1 + kk * 16];
    }
#pragma unroll
    for (int s = 0; s < 4; ++s) {
      bf16x8 (&cur)[8] = (s & 1) ? A1 : A0;
      bf16x8 (&nxt)[8] = (s & 1) ? A0 : A1;
      if (s < 3) {
        const unsigned short* nsrc = Zn + (size_t)(s + 1) * HSTRIDE + zj_base;
#pragma unroll
        for (int kk = 0; kk < 8; ++kk) nxt[kk] = *(const bf16x8*)&nsrc[arow + kk * 16];
      }
      f32x16 acc0 = {}, acc1 = {};
#pragma unroll
      for (int kk = 0; kk < 8; ++kk) {
        acc0 = __builtin_amdgcn_mfma_f32_32x32x16_bf16(cur[kk], XB0[kk], acc0, 0, 0, 0);
        acc1 = __builtin_amdgcn_mfma_f32_32x32x16_bf16(cur[kk], XB1[kk], acc1, 0, 0, 0);
      }
#pragma unroll
      for (int q = 0; q < 16; ++q) {
        maxJ0[q] = fmaxf(maxJ0[q], acc0[q]);
        maxJ1[q] = fmaxf(maxJ1[q], acc1[q]);
      }
    }
  }

  // ---- epilogue: symmetrize via LDS transpose, scale, pow, write both tiles ----
  // P1: Tb[tidx(r,c)] = Pji (or Pii for diag), natural (bj-row, bi-col) orientation
#pragma unroll
  for (int nb = 0; nb < 2; ++nb)
#pragma unroll
    for (int q = 0; q < 16; ++q) {
      int r = R0 + (q & 3) + 8 * (q >> 2) + 4 * fh;
      int c = C0 + nb * 32 + fr;
      float v;
      if (diag)      v = nb ? maxI1[q] : maxI0[q];
      else           v = nb ? maxJ1[q] : maxJ0[q];
      Tb[tidx(r, c)] = f2bf(v);
    }
  __syncthreads();

  const float beta = betap[0];
  const bool bp = (beta != 1.0f);
  float vv[2][16];
#pragma unroll
  for (int nb = 0; nb < 2; ++nb)
#pragma unroll
    for (int q = 0; q < 16; ++q) {
      int r = R0 + (q & 3) + 8 * (q >> 2) + 4 * fh;
      int c = C0 + nb * 32 + fr;
      float a = nb ? maxI1[q] : maxI0[q];
      float b = bf2f(Tb[tidx(c, r)]);      // Pji transposed at (r,c)
      float v = 0.25f * (a + b) + 0.5f;    // ((a+b)/2 + 1)/2
      if (bp) v = powf(v, beta);
      __builtin_nontemporal_store(
          v, &out[(size_t)(bi * TILE + r) * N_NODES + (size_t)(bj * TILE + c)]);
      vv[nb][q] = v;
    }

  if (!diag) {
    __syncthreads();
    // P3: store result transposed (lower tile natural orientation)
#pragma unroll
    for (int nb = 0; nb < 2; ++nb)
#pragma unroll
      for (int q = 0; q < 16; ++q) {
        int r = R0 + (q & 3) + 8 * (q >> 2) + 4 * fh;
        int c = C0 + nb * 32 + fr;
        Tb[tidx(c, r)] = f2bf(vv[nb][q]);
      }
    __syncthreads();
    // P4: coalesced write of mirrored tile
#pragma unroll
    for (int it = 0; it < 32; ++it) {
      int row = it * 4 + (t >> 7);
      int col = t & 127;
      __builtin_nontemporal_store(
          bf2f(Tb[tidx(row, col)]),
          &out[(size_t)(bj * TILE + row) * N_NODES + (size_t)(bi * TILE + col)]);
    }
  }
}

extern "C" void kernel_launch(void* const* d_in, const int* in_sizes, int n_in,
                              void* d_out, int out_size, void* d_ws, size_t ws_size,
                              hipStream_t stream) {
  const float* X = (const float*)d_in[0];
  const float* W = (const float*)d_in[1];
  const float* Z = (const float*)d_in[2];
  const float* beta = (const float*)d_in[3];
  float* out = (float*)d_out;
  char* ws = (char*)d_ws;

  unsigned short* Xen = (unsigned short*)ws;                // 2 MiB bf16 [8192][128]
  unsigned short* Zn  = (unsigned short*)(ws + (2u << 20)); // 8 MiB bf16 [4][8192][128]

  hipLaunchKernelGGL(xw_kernel, dim3(N_NODES / 32), dim3(512), 0, stream, X, W, Xen);
  hipLaunchKernelGGL(znorm_kernel, dim3(N_HEADS * N_NODES / 4), dim3(256), 0, stream, Z, Zn);
  hipLaunchKernelGGL(affinity_kernel, dim3(NPAIR), dim3(512), 0, stream, Xen, Zn, beta, out);
}

// Round 5
// 389.347 us; speedup vs baseline: 1.2438x; 1.2438x over previous
//
#include <hip/hip_runtime.h>
#include <stdint.h>
#include <stddef.h>

#define N_NODES 8192
#define N_FEAT  512
#define EMB     128
#define N_HEADS 4
#define BT      64                      // block tile
#define TG      (N_NODES / BT)          // 128
#define NPAIR   (TG * (TG + 1) / 2)     // 8256 (divisible by 8)

typedef __attribute__((ext_vector_type(8)))  short bf16x8;
typedef __attribute__((ext_vector_type(16))) float f32x16;

__device__ __forceinline__ unsigned short f2bf(float f) {
  union { float f; unsigned int u; } x; x.f = f;
  unsigned int r = (x.u + 0x7FFFu + ((x.u >> 16) & 1u)) >> 16;
  return (unsigned short)r;
}
__device__ __forceinline__ float bf2f(unsigned short u) {
  union { unsigned int u; float f; } x; x.u = ((unsigned int)u) << 16;
  return x.f;
}

// Epilogue transpose buffer (bf16 [64][64]) swizzle: low-conflict in natural
// AND transposed orientation. r*64 + (c ^ (r&31) ^ ((r&4)<<3)).
__device__ __forceinline__ int tidx(int r, int c) {
  return r * 64 + (c ^ (r & 31) ^ ((r & 4) << 3));
}

// fragment-linear flat index (shorts) within one 64-row tile:
// [rb=(n>>5)&1][kk=k>>4][lane=((k>>3)&1)<<5 | (n&31)][e=k&7]
__device__ __forceinline__ size_t frag_flat(int n, int k) {
  return ((size_t)(((n >> 6) * 2 + ((n >> 5) & 1)) * 8 + (k >> 4)) * 64
          + ((((k >> 3) & 1) << 5) | (n & 31))) * 8 + (k & 7);
}

// ---------- kernel 1: X_emb = X@W, row-normalize, bf16, fragment-linear write ----------
__global__ void __launch_bounds__(512) xw_kernel(const float* __restrict__ X,
                                                 const float* __restrict__ W,
                                                 unsigned short* __restrict__ Xf) {
  __shared__ float xs[32][N_FEAT];    // 64KB
  const int t = threadIdx.x;
  const int row0 = blockIdx.x * 32;
#pragma unroll
  for (int i = 0; i < 8; ++i) {
    int e4 = i * 512 + t;             // float4 index, 4096 total
    int row = e4 >> 7;
    int col = (e4 & 127) * 4;
    *(float4*)&xs[row][col] = *(const float4*)&X[(size_t)(row0 + row) * N_FEAT + col];
  }
  __syncthreads();
  const int c0 = (t & 31) * 4;        // 4 consecutive k (emb) values
  const int r0 = (t >> 5) * 2;
  float a00=0.f,a01=0.f,a02=0.f,a03=0.f,a10=0.f,a11=0.f,a12=0.f,a13=0.f;
  for (int k = 0; k < N_FEAT; k += 2) {
    float4 w0 = *(const float4*)&W[(size_t)k * EMB + c0];
    float4 w1 = *(const float4*)&W[(size_t)(k + 1) * EMB + c0];
    float x00 = xs[r0][k],     x01 = xs[r0][k + 1];
    float x10 = xs[r0 + 1][k], x11 = xs[r0 + 1][k + 1];
    a00 += x00*w0.x; a01 += x00*w0.y; a02 += x00*w0.z; a03 += x00*w0.w;
    a10 += x10*w0.x; a11 += x10*w0.y; a12 += x10*w0.z; a13 += x10*w0.w;
    a00 += x01*w1.x; a01 += x01*w1.y; a02 += x01*w1.z; a03 += x01*w1.w;
    a10 += x11*w1.x; a11 += x11*w1.y; a12 += x11*w1.z; a13 += x11*w1.w;
  }
  float s0 = a00*a00 + a01*a01 + a02*a02 + a03*a03;
  float s1 = a10*a10 + a11*a11 + a12*a12 + a13*a13;
#pragma unroll
  for (int off = 16; off >= 1; off >>= 1) {
    s0 += __shfl_xor(s0, off);
    s1 += __shfl_xor(s1, off);
  }
  float inv0 = 1.0f / (sqrtf(s0) + 1e-6f);
  float inv1 = 1.0f / (sqrtf(s1) + 1e-6f);
  union { unsigned short u[4]; uint2 v; } o0, o1;
  o0.u[0]=f2bf(a00*inv0); o0.u[1]=f2bf(a01*inv0); o0.u[2]=f2bf(a02*inv0); o0.u[3]=f2bf(a03*inv0);
  o1.u[0]=f2bf(a10*inv1); o1.u[1]=f2bf(a11*inv1); o1.u[2]=f2bf(a12*inv1); o1.u[3]=f2bf(a13*inv1);
  int n0 = row0 + r0;
  *(uint2*)&Xf[frag_flat(n0, c0)] = o0.v;        // c0&7 in {0,4} -> 8B aligned
  *(uint2*)&Xf[frag_flat(n0 + 1, c0)] = o1.v;
}

// ---------- kernel 2: Z row-normalize + bf16, fragment-linear write ----------
__global__ void __launch_bounds__(256) znorm_kernel(const float* __restrict__ in,
                                                    unsigned short* __restrict__ Zf) {
  const int row = blockIdx.x * 4 + (threadIdx.x >> 6);   // global row in [0, 4*8192)
  const int lane = threadIdx.x & 63;
  float2 v = *(const float2*)&in[(size_t)row * EMB + lane * 2];
  float ss = v.x * v.x + v.y * v.y;
#pragma unroll
  for (int off = 32; off >= 1; off >>= 1) ss += __shfl_xor(ss, off);
  const float s = 1.0f / (sqrtf(ss) + 1e-6f);
  union { unsigned short u[2]; unsigned int w; } o;
  o.u[0] = f2bf(v.x * s);
  o.u[1] = f2bf(v.y * s);
  const int h = row >> 13;
  const int n = row & 8191;
  const int c = lane * 2;                                // c&7 in {0,2,4,6} -> 4B aligned
  size_t flat = ((size_t)h << 20) + frag_flat(n, c);     // head stride = 128 tiles * 8192
  *(unsigned int*)&Zf[flat] = o.w;
}

// ---------- kernel 3: fused affinity — fragment-streaming, no main-loop LDS ----------
__global__ void __launch_bounds__(256, 4)
affinity_kernel(const unsigned short* __restrict__ Xf,
                const unsigned short* __restrict__ Zf,
                const float* __restrict__ betap,
                float* __restrict__ out) {
  __shared__ unsigned short Tb[BT * BT];   // 8KB transpose buffer

  // XCD-bijective swizzle (8256 % 8 == 0)
  int bid = blockIdx.x;
  int p = (bid & 7) * (NPAIR / 8) + (bid >> 3);
  // triangular decode p -> (bi <= bj)
  int i = (int)(((float)(2 * TG + 1) -
                 sqrtf((float)((2 * TG + 1) * (2 * TG + 1) - 8 * p))) * 0.5f);
  if (i < 0) i = 0;
  if (i > TG - 1) i = TG - 1;
  while (i > 0 && i * TG - i * (i - 1) / 2 > p) --i;
  while ((i + 1) * TG - (i + 1) * i / 2 <= p) ++i;
  const int bi = i;
  const int bj = i + (p - (i * TG - i * (i - 1) / 2));
  const bool diag = (bi == bj);

  const int t = threadIdx.x;
  const int lane = t & 63;
  const int wid = t >> 6;            // 4 waves: 2 row-halves x 2 col-halves
  const int rb = wid >> 1;
  const int cb = wid & 1;
  const int R0 = rb * 32, C0 = cb * 32;
  const int fr = lane & 31, fh = lane >> 5;
  const int lo = lane * 8;           // lane offset (shorts) inside a 512-short kk-block

  // B fragments (X cols of bj), coalesced 1KB/load
  const unsigned short* xb = Xf + ((size_t)(bj * 2 + cb) << 12);
  bf16x8 XB[8];
#pragma unroll
  for (int kk = 0; kk < 8; ++kk) XB[kk] = *(const bf16x8*)&xb[kk * 512 + lo];

  f32x16 maxI;
#pragma unroll
  for (int q = 0; q < 16; ++q) maxI[q] = -3.0e38f;

  // ---- phase I: P_ij = max_h Z[h][bi-rows] . Xj^T ----
  const size_t aoffI = ((size_t)(bi * 2 + rb)) << 12;
#pragma unroll
  for (int h = 0; h < N_HEADS; ++h) {
    const unsigned short* ab = Zf + ((size_t)h << 20) + aoffI;
    f32x16 acc = {};
#pragma unroll
    for (int kk = 0; kk < 8; ++kk) {
      bf16x8 a = *(const bf16x8*)&ab[kk * 512 + lo];
      acc = __builtin_amdgcn_mfma_f32_32x32x16_bf16(a, XB[kk], acc, 0, 0, 0);
    }
#pragma unroll
    for (int q = 0; q < 16; ++q) maxI[q] = fmaxf(maxI[q], acc[q]);
  }

  // ---- phase J: P_ji = max_h Z[h][bj-rows] . Xi^T ----
  f32x16 maxJ;
#pragma unroll
  for (int q = 0; q < 16; ++q) maxJ[q] = -3.0e38f;
  if (!diag) {
    const unsigned short* xb2 = Xf + ((size_t)(bi * 2 + cb) << 12);
#pragma unroll
    for (int kk = 0; kk < 8; ++kk) XB[kk] = *(const bf16x8*)&xb2[kk * 512 + lo];
    const size_t aoffJ = ((size_t)(bj * 2 + rb)) << 12;
#pragma unroll
    for (int h = 0; h < N_HEADS; ++h) {
      const unsigned short* ab = Zf + ((size_t)h << 20) + aoffJ;
      f32x16 acc = {};
#pragma unroll
      for (int kk = 0; kk < 8; ++kk) {
        bf16x8 a = *(const bf16x8*)&ab[kk * 512 + lo];
        acc = __builtin_amdgcn_mfma_f32_32x32x16_bf16(a, XB[kk], acc, 0, 0, 0);
      }
#pragma unroll
      for (int q = 0; q < 16; ++q) maxJ[q] = fmaxf(maxJ[q], acc[q]);
    }
  }

  // ---- epilogue: symmetrize via LDS transpose, scale, pow, write both tiles ----
  // P1: Tb = P_ji (or P_ii for diag) at natural (r,c)
#pragma unroll
  for (int q = 0; q < 16; ++q) {
    int r = R0 + (q & 3) + 8 * (q >> 2) + 4 * fh;
    int c = C0 + fr;
    Tb[tidx(r, c)] = f2bf(diag ? maxI[q] : maxJ[q]);
  }
  __syncthreads();

  const float beta = betap[0];
  const bool bp = (beta != 1.0f);
  float vv[16];
#pragma unroll
  for (int q = 0; q < 16; ++q) {
    int r = R0 + (q & 3) + 8 * (q >> 2) + 4 * fh;
    int c = C0 + fr;
    float a = maxI[q];
    float b = bf2f(Tb[tidx(c, r)]);      // P_ji^T at (r,c)
    float v = 0.25f * (a + b) + 0.5f;    // ((a+b)/2 + 1)/2
    if (bp) v = powf(v, beta);
    __builtin_nontemporal_store(
        v, &out[(size_t)(bi * BT + r) * N_NODES + (size_t)(bj * BT + c)]);
    vv[q] = v;
  }

  if (!diag) {
    __syncthreads();
    // P3: store result transposed
#pragma unroll
    for (int q = 0; q < 16; ++q) {
      int r = R0 + (q & 3) + 8 * (q >> 2) + 4 * fh;
      int c = C0 + fr;
      Tb[tidx(c, r)] = f2bf(vv[q]);
    }
    __syncthreads();
    // P4: coalesced write of mirrored tile
#pragma unroll
    for (int it = 0; it < 16; ++it) {
      int row = it * 4 + (t >> 6);
      int col = t & 63;
      __builtin_nontemporal_store(
          bf2f(Tb[tidx(row, col)]),
          &out[(size_t)(bj * BT + row) * N_NODES + (size_t)(bi * BT + col)]);
    }
  }
}

extern "C" void kernel_launch(void* const* d_in, const int* in_sizes, int n_in,
                              void* d_out, int out_size, void* d_ws, size_t ws_size,
                              hipStream_t stream) {
  const float* X = (const float*)d_in[0];
  const float* W = (const float*)d_in[1];
  const float* Z = (const float*)d_in[2];
  const float* beta = (const float*)d_in[3];
  float* out = (float*)d_out;
  char* ws = (char*)d_ws;

  unsigned short* Xf = (unsigned short*)ws;                // 2 MiB frag-linear bf16
  unsigned short* Zf = (unsigned short*)(ws + (2u << 20)); // 8 MiB frag-linear bf16

  hipLaunchKernelGGL(xw_kernel, dim3(N_NODES / 32), dim3(512), 0, stream, X, W, Xf);
  hipLaunchKernelGGL(znorm_kernel, dim3(N_HEADS * N_NODES / 4), dim3(256), 0, stream, Z, Zf);
  hipLaunchKernelGGL(affinity_kernel, dim3(NPAIR), dim3(256), 0, stream, Xf, Zf, beta, out);
}